// Round 7
// baseline (14.661 us; speedup 1.0000x reference)
//
#include <hip/hip_runtime.h>

// FCOSLayer_22840636080477 — fused YOLO-style loss on MI355X (round 7).
// vs R6: 256 blocks x 384 threads (same 1536 waves, 6 waves/CU) — halves
// launch ramp, per-block preproc redundancy, publish atomics; tail becomes
// ONE atomic load per thread (single pass over 256 slots with 384 threads).

constexpr int NA_   = 3;
constexpr int NG_   = 64;
constexpr int NCLS_ = 80;
constexpr int NK_   = 50;
constexpr int NCH_  = 85;    // 5 + NCLS
constexpr int BLOCK_ = 384;  // 6 waves
constexpr int GRID_  = 256;  // 1 block/CU
constexpr int CPB_   = 768;  // cells per block (2 per thread, adjacent)
constexpr unsigned MAGIC_ = 0x5A17C0DEu;

__device__ __forceinline__ float softplusf_(float x) {
    return fmaxf(x, 0.0f) + log1pf(expf(-fabsf(x)));
}

__global__ __launch_bounds__(BLOCK_) void fcos_loss_kernel(
    const float* __restrict__ raw,
    const float* __restrict__ labels,
    const float* __restrict__ anchors,
    const int*   __restrict__ img_size_p,
    float*       __restrict__ out,
    unsigned long long* __restrict__ slots)
{
    __shared__ float4 s_box[NK_];        // compacted valid_row boxes (corners)
    __shared__ float  s_a375[NK_];       // compacted 0.375*area
    __shared__ float  s_tgt[NK_][4];     // per-ORIGINAL-label ltrb target
    __shared__ int    s_cls[NK_];        // per-ORIGINAL-label class
    __shared__ int    s_cm[CPB_];        // local cell -> label idx (or -1)
    __shared__ int    s_nvr;             // count of valid_row labels
    __shared__ int    s_hasvalid;
    __shared__ float  s_wsum[BLOCK_ / 64];

    const int tid  = threadIdx.x;
    const int lane = tid & 63;
    const int bid  = blockIdx.x;
    const int b    = bid >> 4;                  // 16 blocks per batch
    const int base = (bid & 15) * CPB_;
    const float inv_img = 1.0f / (float)img_size_p[0];

    // ---- wave-0 label loads FIRST, then everyone's channel loads ----
    float c0l = 0, lx = 0, ly = 0, lw = 0, lh = 0;
    if (tid < NK_) {
        const float* lab = labels + ((size_t)b * NK_ + tid) * 5;
        c0l = lab[0]; lx = lab[1]; ly = lab[2]; lw = lab[3]; lh = lab[4];
    }

    const int cid0 = base + 2 * tid;            // even; pair never straddles a/row
    const int a0 = cid0 >> 12, rr = cid0 & 4095;
    const float* cbase = raw + (((size_t)(b * NA_ + a0) * NCH_) << 12) + rr;
    const float2 ch0 = *(const float2*)(cbase);
    const float2 ch1 = *(const float2*)(cbase + 4096);
    const float2 ch2 = *(const float2*)(cbase + 2 * 4096);
    const float2 ch3 = *(const float2*)(cbase + 3 * 4096);
    const float2 ch4 = *(const float2*)(cbase + 4 * 4096);

    // ---- wave 0: init s_cm, label preproc with compaction + scatter ----
    if (tid < 64) {
        #pragma unroll
        for (int q = 0; q < CPB_ / 64; ++q) s_cm[lane + 64 * q] = -1;

        bool vrow = false, val = false;
        int ti = 0, tj = 0, bn = 0;
        if (lane < NK_) {
            vrow = (c0l + lx + ly + lw + lh) > 0.0f;
            float tx = lx * NG_, ty = ly * NG_;
            ti = (int)tx; tj = (int)ty;

            int best = 0; float bi = -1.0f;
            #pragma unroll
            for (int n = 0; n < 9; ++n) {
                float aw = anchors[n*2]     * inv_img;
                float ah = anchors[n*2 + 1] * inv_img;
                float inter = fminf(lw, aw) * fminf(lh, ah);
                float uni   = lw*lh + aw*ah - inter;
                float iou   = inter / (uni + 1e-16f);
                if (iou > bi) { bi = iou; best = n; }
            }
            bn  = best % NA_;
            val = vrow && (best < NA_) &&
                  ti >= 0 && ti < NG_ && tj >= 0 && tj < NG_;

            if (val) {
                float w64 = lw * NG_, h64 = lh * NG_;
                float xc = floorf(tx) + 0.5f, yc = floorf(ty) + 0.5f;
                float lt = fmaxf(xc - (tx - w64*0.5f), 0.0f) * (1.0f/NG_);
                float tt = fmaxf(yc - (ty - h64*0.5f), 0.0f) * (1.0f/NG_);
                float rt = fmaxf(tx + w64*0.5f - xc, 0.0f) * (1.0f/NG_);
                float bt = fmaxf(ty + h64*0.5f - yc, 0.0f) * (1.0f/NG_);
                float awn = anchors[bn*2] * inv_img;
                s_tgt[lane][0] = logf(lt / awn + 1e-16f);
                s_tgt[lane][1] = logf(tt / awn + 1e-16f);
                s_tgt[lane][2] = logf(rt / awn + 1e-16f);
                s_tgt[lane][3] = logf(bt / awn + 1e-16f);
                s_cls[lane] = (int)c0l;
            }
        }
        unsigned long long bbv = __ballot(vrow);
        unsigned long long bba = __ballot(val);
        if (lane < NK_ && vrow) {
            int pos = (int)__popcll(bbv & ((1ull << lane) - 1ull));
            s_box[pos]  = make_float4(lx - lw*0.5f, ly - lh*0.5f,
                                      lx + lw*0.5f, ly + lh*0.5f);
            s_a375[pos] = 0.375f * lw * lh;
        }
        if (lane < NK_ && val) {
            int tcid = (bn << 12) | (tj << 6) | ti;
            unsigned loc = (unsigned)(tcid - base);
            if (loc < (unsigned)CPB_) s_cm[loc] = lane;
        }
        if (lane == 0) {
            s_nvr      = (int)__popcll(bbv);
            s_hasvalid = (bba != 0ull) ? 1 : 0;
        }
    }

    // ---- decode both cells BEFORE the barrier (waves 1-5 overlap preproc) ----
    const float scale = 8.0f * inv_img;
    const float aw0 = anchors[a0 * 2];
    const int i0 = rr & 63, j0 = rr >> 6;

    float tlx0, tly0, brx0, bry0, t3750;
    float tlx1, tly1, brx1, bry1, t3751;
    {
        float ls = expf(ch0.x)*aw0*0.125f, ts = expf(ch1.x)*aw0*0.125f;
        float rs = expf(ch2.x)*aw0*0.125f, bs = expf(ch3.x)*aw0*0.125f;
        float cx = ((i0 + 0.5f) + (rs - ls)*0.5f) * scale;
        float cy = ((j0 + 0.5f) + (bs - ts)*0.5f) * scale;
        float pw = (ls + rs) * scale, ph = (ts + bs) * scale;
        tlx0 = cx - pw*0.5f; tly0 = cy - ph*0.5f;
        brx0 = cx + pw*0.5f; bry0 = cy + ph*0.5f;
        t3750 = 0.375f * (pw * ph + 1e-16f);
    }
    {
        float ls = expf(ch0.y)*aw0*0.125f, ts = expf(ch1.y)*aw0*0.125f;
        float rs = expf(ch2.y)*aw0*0.125f, bs = expf(ch3.y)*aw0*0.125f;
        float cx = ((i0 + 1.5f) + (rs - ls)*0.5f) * scale;
        float cy = ((j0 + 0.5f) + (bs - ts)*0.5f) * scale;
        float pw = (ls + rs) * scale, ph = (ts + bs) * scale;
        tlx1 = cx - pw*0.5f; tly1 = cy - ph*0.5f;
        brx1 = cx + pw*0.5f; bry1 = cy + ph*0.5f;
        t3751 = 0.375f * (pw * ph + 1e-16f);
    }
    __syncthreads();

    // ---- match via LDS (known BEFORE the IoU loop) ----
    const int km0 = s_cm[2*tid], km1 = s_cm[2*tid + 1];
    const bool gt0 = km0 >= 0, gt1 = km1 >= 0;
    const int cls0 = gt0 ? s_cls[km0] : 0;
    const int cls1 = gt1 ? s_cls[km1] : 0;

    float lsum = 0.0f;
    if (gt0) {
        float d0 = ch0.x - s_tgt[km0][0], d1 = ch1.x - s_tgt[km0][1];
        float d2 = ch2.x - s_tgt[km0][2], d3 = ch3.x - s_tgt[km0][3];
        lsum += d0*d0 + d1*d1 + d2*d2 + d3*d3;
    }
    if (gt1) {
        float d0 = ch0.y - s_tgt[km1][0], d1 = ch1.y - s_tgt[km1][1];
        float d2 = ch2.y - s_tgt[km1][2], d3 = ch3.y - s_tgt[km1][3];
        lsum += d0*d0 + d1*d1 + d2*d2 + d3*d3;
    }

    // ---- 2-slot class-logit prefetch (loads in flight across IoU loop) ----
    unsigned long long gA = __ballot(gt0), gB = __ballot(gt1);
    int scid0 = 0, scls0 = 0, scid1 = 0, scls1 = 0;
    bool h0 = false, h1 = false;
    float px0 = 0, py0 = 0, px1 = 0, py1 = 0;

    if (gA) { int L = (int)__ffsll(gA) - 1; gA &= gA - 1;
              scid0 = __shfl(cid0, L);     scls0 = __shfl(cls0, L); h0 = true; }
    else if (gB) { int L = (int)__ffsll(gB) - 1; gB &= gB - 1;
              scid0 = __shfl(cid0 + 1, L); scls0 = __shfl(cls1, L); h0 = true; }
    if (h0) {
        int aa = scid0 >> 12, rc = scid0 & 4095;
        const float* clp = raw + (((size_t)(b*NA_ + aa) * NCH_ + 5) << 12) + rc;
        px0 = clp[(size_t)lane << 12];
        py0 = (lane < NCLS_ - 64) ? clp[(size_t)(lane + 64) << 12] : 0.0f;
    }
    if (gA) { int L = (int)__ffsll(gA) - 1; gA &= gA - 1;
              scid1 = __shfl(cid0, L);     scls1 = __shfl(cls0, L); h1 = true; }
    else if (gB) { int L = (int)__ffsll(gB) - 1; gB &= gB - 1;
              scid1 = __shfl(cid0 + 1, L); scls1 = __shfl(cls1, L); h1 = true; }
    if (h1) {
        int aa = scid1 >> 12, rc = scid1 & 4095;
        const float* clp = raw + (((size_t)(b*NA_ + aa) * NCH_ + 5) << 12) + rc;
        px1 = clp[(size_t)lane << 12];
        py1 = (lane < NCLS_ - 64) ? clp[(size_t)(lane + 64) << 12] : 0.0f;
    }

    // ---- IoU ignore loop over COMPACTED valid labels ----
    const int nv = s_nvr;
    bool ign0 = false, ign1 = false;
    #pragma unroll 2
    for (int k = 0; k < nv; ++k) {
        float4 bx = s_box[k];
        float  ak = s_a375[k];
        {
            float iw = fminf(brx0, bx.z) - fmaxf(tlx0, bx.x);
            float ih = fminf(bry0, bx.w) - fmaxf(tly0, bx.y);
            float inter = fmaxf(iw, 0.0f) * fmaxf(ih, 0.0f);
            ign0 |= inter > (t3750 + ak);
        }
        {
            float iw = fminf(brx1, bx.z) - fmaxf(tlx1, bx.x);
            float ih = fminf(bry1, bx.w) - fmaxf(tly1, bx.y);
            float inter = fmaxf(iw, 0.0f) * fmaxf(ih, 0.0f);
            ign1 |= inter > (t3751 + ak);
        }
    }

    // ---- conf BCE ----
    const int hv = s_hasvalid;
    if ((hv ? !ign0 : true) || gt0) lsum += gt0 ? softplusf_(-ch4.x) : softplusf_(ch4.x);
    if ((hv ? !ign1 : true) || gt1) lsum += gt1 ? softplusf_(-ch4.y) : softplusf_(ch4.y);

    // ---- consume prefetched class BCE ----
    if (h0) {
        lsum += (lane == scls0) ? softplusf_(-px0) : softplusf_(px0);
        if (lane < NCLS_ - 64)
            lsum += (lane + 64 == scls0) ? softplusf_(-py0) : softplusf_(py0);
    }
    if (h1) {
        lsum += (lane == scls1) ? softplusf_(-px1) : softplusf_(px1);
        if (lane < NCLS_ - 64)
            lsum += (lane + 64 == scls1) ? softplusf_(-py1) : softplusf_(py1);
    }
    // rare: >2 gt cells in wave
    while (gA) {
        int L = (int)__ffsll(gA) - 1; gA &= gA - 1;
        int scid = __shfl(cid0, L), scls = __shfl(cls0, L);
        int aa = scid >> 12, rc = scid & 4095;
        const float* clp = raw + (((size_t)(b*NA_ + aa) * NCH_ + 5) << 12) + rc;
        float x = clp[(size_t)lane << 12];
        lsum += (lane == scls) ? softplusf_(-x) : softplusf_(x);
        if (lane < NCLS_ - 64) {
            float y = clp[(size_t)(lane + 64) << 12];
            lsum += (lane + 64 == scls) ? softplusf_(-y) : softplusf_(y);
        }
    }
    while (gB) {
        int L = (int)__ffsll(gB) - 1; gB &= gB - 1;
        int scid = __shfl(cid0 + 1, L), scls = __shfl(cls1, L);
        int aa = scid >> 12, rc = scid & 4095;
        const float* clp = raw + (((size_t)(b*NA_ + aa) * NCH_ + 5) << 12) + rc;
        float x = clp[(size_t)lane << 12];
        lsum += (lane == scls) ? softplusf_(-x) : softplusf_(x);
        if (lane < NCLS_ - 64) {
            float y = clp[(size_t)(lane + 64) << 12];
            lsum += (lane + 64 == scls) ? softplusf_(-y) : softplusf_(y);
        }
    }

    // ---- block reduce ----
    #pragma unroll
    for (int off = 32; off > 0; off >>= 1) lsum += __shfl_down(lsum, off);
    if (lane == 0) s_wsum[tid >> 6] = lsum;
    __syncthreads();

    // ---- single-atomic packed publish: {MAGIC | bits(partial)} ----
    if (tid == 0) {
        float blocksum = 0.0f;
        #pragma unroll
        for (int q = 0; q < BLOCK_ / 64; ++q) blocksum += s_wsum[q];
        unsigned long long packed =
            ((unsigned long long)MAGIC_ << 32) |
            (unsigned long long)__float_as_uint(blocksum);
        atomicExch(&slots[bid], packed);
    }

    // ---- block GRID-1: one atomic load per thread, spin on stragglers ----
    if (bid == GRID_ - 1) {
        float t = 0.0f;
        if (tid < GRID_) {
            unsigned long long v = atomicOr(&slots[tid], 0ull);
            while ((unsigned)(v >> 32) != MAGIC_) {
                __builtin_amdgcn_s_sleep(8);
                v = atomicOr(&slots[tid], 0ull);
            }
            t = __uint_as_float((unsigned)v);
        }
        #pragma unroll
        for (int off = 32; off > 0; off >>= 1) t += __shfl_down(t, off);
        __syncthreads();
        if (lane == 0) s_wsum[tid >> 6] = t;
        __syncthreads();
        if (tid == 0) {
            float r = 0.0f;
            #pragma unroll
            for (int q = 0; q < BLOCK_ / 64; ++q) r += s_wsum[q];
            out[0] = r;
        }
    }
}

extern "C" void kernel_launch(void* const* d_in, const int* in_sizes, int n_in,
                              void* d_out, int out_size, void* d_ws, size_t ws_size,
                              hipStream_t stream) {
    const float* raw     = (const float*)d_in[0];
    const float* labels  = (const float*)d_in[1];
    const float* anchors = (const float*)d_in[2];
    const int*   img     = (const int*)d_in[3];
    float* out = (float*)d_out;
    unsigned long long* slots = (unsigned long long*)d_ws;

    fcos_loss_kernel<<<dim3(GRID_), dim3(BLOCK_), 0, stream>>>(
        raw, labels, anchors, img, out, slots);
}